// Round 6
// baseline (492.838 us; speedup 1.0000x reference)
//
#include <hip/hip_runtime.h>
#include <hip/hip_fp16.h>

#define NCH 128

typedef short bf16x8 __attribute__((ext_vector_type(8)));
typedef float f32x4 __attribute__((ext_vector_type(4)));

__device__ __forceinline__ unsigned short f32_to_bf16_rne(float f) {
    unsigned u = __float_as_uint(f);
    unsigned r = u + 0x7FFFu + ((u >> 16) & 1u);
    return (unsigned short)(r >> 16);
}
// trunc-split: hi = trunc16(f), lo = rne(f - hi). |lo| <= 2^-8|f|.
__device__ __forceinline__ void split_bf16(float f, unsigned short& hi, unsigned short& lo) {
    unsigned u = __float_as_uint(f);
    hi = (unsigned short)(u >> 16);
    float l = f - __uint_as_float(u & 0xFFFF0000u);
    lo = f32_to_bf16_rne(l);
}

// ---------------- CSR build ----------------
// After deg+scan: off[d] = start of node d. fill bumps off[d]; after: off[d] = inclusive end.

__global__ void gin_deg_kernel(const int* __restrict__ dst, int* __restrict__ off, int E) {
    int e = blockIdx.x * 256 + threadIdx.x;
    if (e < E) atomicAdd(&off[dst[e] + 1], 1);
}

__global__ void gin_scan1(const int* __restrict__ off, int* __restrict__ part, int n) {
    __shared__ int red[256];
    int t = threadIdx.x;
    int base = blockIdx.x * 2048 + t * 8;
    int s = 0;
    if (base + 8 <= n) {
        #pragma unroll
        for (int i = 0; i < 8; ++i) s += off[base + i];
    } else {
        for (int i = 0; i < 8; ++i) { int idx = base + i; if (idx < n) s += off[idx]; }
    }
    red[t] = s;
    __syncthreads();
    #pragma unroll
    for (int o = 128; o > 0; o >>= 1) {
        if (t < o) red[t] += red[t + o];
        __syncthreads();
    }
    if (t == 0) part[blockIdx.x] = red[0];
}

__global__ void gin_scan2(int* __restrict__ part, int nb) {
    __shared__ int sh[256];
    int t = threadIdx.x;
    int v = (t < nb) ? part[t] : 0;
    sh[t] = v;
    __syncthreads();
    #pragma unroll
    for (int o = 1; o < 256; o <<= 1) {
        int u = (t >= o) ? sh[t - o] : 0;
        __syncthreads();
        sh[t] += u;
        __syncthreads();
    }
    if (t < nb) part[t] = sh[t] - v;
}

__global__ void gin_scan3(int* __restrict__ off, const int* __restrict__ part, int n) {
    __shared__ int red[256];
    int t = threadIdx.x;
    int base = blockIdx.x * 2048 + t * 8;
    int loc[8];
    int s = 0;
    #pragma unroll
    for (int i = 0; i < 8; ++i) {
        int idx = base + i;
        int v = (idx < n) ? off[idx] : 0;
        s += v;
        loc[i] = s;
    }
    red[t] = s;
    __syncthreads();
    #pragma unroll
    for (int o = 1; o < 256; o <<= 1) {
        int u = (t >= o) ? red[t - o] : 0;
        __syncthreads();
        red[t] += u;
        __syncthreads();
    }
    int offset = part[blockIdx.x] + red[t] - s;
    #pragma unroll
    for (int i = 0; i < 8; ++i) {
        int idx = base + i;
        if (idx < n) off[idx] = loc[i] + offset;
    }
}

__global__ void gin_fill_kernel(const int* __restrict__ src, const int* __restrict__ dst,
                                int* __restrict__ off, int* __restrict__ csr, int E) {
    int e = blockIdx.x * 256 + threadIdx.x;
    if (e < E) {
        int d = dst[e];
        int p = atomicAdd(&off[d], 1);
        csr[p] = src[e];
    }
}

// ---------------- x -> fp16 ----------------
__global__ void gin_f2h_kernel(const float* __restrict__ x, __half* __restrict__ xh, int n4) {
    int i = blockIdx.x * 256 + threadIdx.x;
    if (i >= n4) return;
    float4 v = ((const float4*)x)[i];
    union { __half h[4]; uint2 u; } o;
    o.h[0] = __float2half(v.x); o.h[1] = __float2half(v.y);
    o.h[2] = __float2half(v.z); o.h[3] = __float2half(v.w);
    ((uint2*)xh)[i] = o.u;
}

// ---------------- weight pre-pack into MFMA B-fragment order (bf16 hi/lo) ----------------
__global__ void gin_pack_kernel(const float* __restrict__ W, int K, int N,
                                unsigned short* __restrict__ out) {
    int idx = blockIdx.x * 256 + threadIdx.x;
    int KC = K / 32, NT = N / 16;
    int total = 2 * KC * NT * 64 * 8;
    if (idx >= total) return;
    int j = idx & 7;
    int l = (idx >> 3) & 63;
    int v = idx >> 9;
    int nt = v % NT; v /= NT;
    int kc = v % KC;
    int spl = v / KC;
    int k = kc * 32 + (l >> 4) * 8 + j;
    int n = nt * 16 + (l & 15);
    float w = W[(size_t)k * N + n];
    unsigned short hi, lo;
    split_bf16(w, hi, lo);
    out[idx] = (spl == 0) ? hi : lo;
}

// ---------------- aggregation: z = (1+eps)*h + mean_neigh -> (zh, zl) bf16 split ----------------
__global__ __launch_bounds__(256)
void gin_agg_kernel(const __half* __restrict__ h, const int* __restrict__ offend,
                    const int* __restrict__ csr, const float* __restrict__ eps, int layer,
                    unsigned short* __restrict__ zh, unsigned short* __restrict__ zl, int n) {
    int node = blockIdx.x * 8 + (threadIdx.x >> 5);
    if (node >= n) return;
    int lane = threadIdx.x & 31;
    int lo = node ? offend[node - 1] : 0;
    int hi = offend[node];

    float s0 = 0.f, s1 = 0.f, s2 = 0.f, s3 = 0.f;
    float t0 = 0.f, t1 = 0.f, t2 = 0.f, t3 = 0.f;
    int e = lo;
    for (; e + 1 < hi; e += 2) {
        int a = csr[e], b = csr[e + 1];
        uint2 ra = *(const uint2*)(h + (size_t)a * NCH + lane * 4);
        uint2 rb = *(const uint2*)(h + (size_t)b * NCH + lane * 4);
        float2 a0 = __half22float2(*(__half2*)&ra.x);
        float2 a1 = __half22float2(*(__half2*)&ra.y);
        float2 b0 = __half22float2(*(__half2*)&rb.x);
        float2 b1 = __half22float2(*(__half2*)&rb.y);
        s0 += a0.x; s1 += a0.y; s2 += a1.x; s3 += a1.y;
        t0 += b0.x; t1 += b0.y; t2 += b1.x; t3 += b1.y;
    }
    if (e < hi) {
        int a = csr[e];
        uint2 ra = *(const uint2*)(h + (size_t)a * NCH + lane * 4);
        float2 a0 = __half22float2(*(__half2*)&ra.x);
        float2 a1 = __half22float2(*(__half2*)&ra.y);
        s0 += a0.x; s1 += a0.y; s2 += a1.x; s3 += a1.y;
    }
    float invd = 1.0f / fmaxf((float)(hi - lo), 1.0f);
    uint2 rs = *(const uint2*)(h + (size_t)node * NCH + lane * 4);
    float2 x0 = __half22float2(*(__half2*)&rs.x);
    float2 x1 = __half22float2(*(__half2*)&rs.y);
    float e1 = 1.0f + eps[layer];
    float z0 = e1 * x0.x + (s0 + t0) * invd;
    float z1 = e1 * x0.y + (s1 + t1) * invd;
    float z2 = e1 * x1.x + (s2 + t2) * invd;
    float z3 = e1 * x1.y + (s3 + t3) * invd;

    ushort4 hv, lv;
    split_bf16(z0, hv.x, lv.x);
    split_bf16(z1, hv.y, lv.y);
    split_bf16(z2, hv.z, lv.z);
    split_bf16(z3, hv.w, lv.w);
    *(ushort4*)(zh + (size_t)node * NCH + lane * 4) = hv;
    *(ushort4*)(zl + (size_t)node * NCH + lane * 4) = lv;
}

// ---------------- fused 2-GEMM MLP on matrix cores (split-bf16, 3 MFMA terms) ----------------
// 256 threads = 4 waves, 32 rows/wave (2 row-tiles), 128 rows/block. No barriers:
// GEMM1->GEMM2 transpose through wave-private 32x36 f32 LDS scratch, interleaved
// with GEMM2's k-loop (32-col window). Weight B-frags amortized over 2 row-tiles
// (halves L2 weight traffic vs 16 rows/wave). No min-occupancy bound: VGPR budget
// free for acc[2][8]+acc2[2][8] and load hoisting.
template <int N1, int N2, typename OutT>
__global__ __launch_bounds__(256)
void gin_mlp_mfma(const unsigned short* __restrict__ Zh, const unsigned short* __restrict__ Zl,
                  const unsigned short* __restrict__ PW1, const float* __restrict__ B1,
                  const unsigned short* __restrict__ PW2, const float* __restrict__ B2,
                  OutT* __restrict__ Out, int nrows) {
    constexpr int K1 = 128;
    constexpr int KC1 = K1 / 32, NT1 = N1 / 16, KC2 = N1 / 32, NT2 = N2 / 16;
    constexpr int SS = 36;  // scratch f32 row stride
    __shared__ __align__(16) float Scr[4 * 32 * SS];

    const int tid = threadIdx.x;
    const int w = tid >> 6;
    const int l = tid & 63;
    const int lr = l & 15;   // A-row / B-col / C-col within 16x16 tile
    const int lg = l >> 4;   // k-group; C-row = lg*4+r
    const int m0 = blockIdx.x * 128 + w * 32;  // this wave's 32-row band
    float* sw = &Scr[w * 32 * SS];

    // ---- GEMM1: T = leaky(Z @ W1 + b1) ----
    f32x4 acc[2][NT1];
    #pragma unroll
    for (int rt = 0; rt < 2; ++rt)
        #pragma unroll
        for (int nt = 0; nt < NT1; ++nt) acc[rt][nt] = {0.f, 0.f, 0.f, 0.f};

    #pragma unroll
    for (int kc = 0; kc < KC1; ++kc) {
        bf16x8 ah[2], al[2];
        #pragma unroll
        for (int rt = 0; rt < 2; ++rt) {
            int row = m0 + rt * 16 + lr;
            if (row < nrows) {
                size_t zo = (size_t)row * K1 + kc * 32 + lg * 8;
                ah[rt] = *(const bf16x8*)(Zh + zo);
                al[rt] = *(const bf16x8*)(Zl + zo);
            } else {
                ah[rt] = (bf16x8){0,0,0,0,0,0,0,0};
                al[rt] = (bf16x8){0,0,0,0,0,0,0,0};
            }
        }
        #pragma unroll
        for (int nt = 0; nt < NT1; ++nt) {
            const unsigned short* pb = PW1 + (((size_t)kc * NT1 + nt) * 64 + l) * 8;
            bf16x8 bh = *(const bf16x8*)pb;
            bf16x8 bl = *(const bf16x8*)(pb + (size_t)KC1 * NT1 * 512);
            #pragma unroll
            for (int rt = 0; rt < 2; ++rt) {
                acc[rt][nt] = __builtin_amdgcn_mfma_f32_16x16x32_bf16(ah[rt], bh, acc[rt][nt], 0, 0, 0);
                acc[rt][nt] = __builtin_amdgcn_mfma_f32_16x16x32_bf16(ah[rt], bl, acc[rt][nt], 0, 0, 0);
                acc[rt][nt] = __builtin_amdgcn_mfma_f32_16x16x32_bf16(al[rt], bh, acc[rt][nt], 0, 0, 0);
            }
        }
    }

    // ---- GEMM2 interleaved with epilogue-1 (no barrier, 32-col scratch window) ----
    f32x4 acc2[2][NT2];
    #pragma unroll
    for (int rt = 0; rt < 2; ++rt)
        #pragma unroll
        for (int nt = 0; nt < NT2; ++nt) acc2[rt][nt] = {0.f, 0.f, 0.f, 0.f};

    #pragma unroll
    for (int kc = 0; kc < KC2; ++kc) {
        // publish T cols kc*32..+31 (tiles nt1 = 2kc, 2kc+1), bias+leaky -> scratch
        #pragma unroll
        for (int rt = 0; rt < 2; ++rt) {
            #pragma unroll
            for (int t = 0; t < 2; ++t) {
                int nt = kc * 2 + t;
                float bb = B1[nt * 16 + lr];
                #pragma unroll
                for (int r = 0; r < 4; ++r) {
                    float v = acc[rt][nt][r] + bb;
                    v = v > 0.f ? v : 0.01f * v;
                    sw[(rt * 16 + lg * 4 + r) * SS + t * 16 + lr] = v;
                }
            }
        }
        // read back as A-fragments (wave-internal; DS in-order + lgkmcnt)
        bf16x8 ah[2], al[2];
        #pragma unroll
        for (int rt = 0; rt < 2; ++rt) {
            const float* tp = &sw[(rt * 16 + lr) * SS + lg * 8];
            f32x4 v0 = *(const f32x4*)tp;
            f32x4 v1 = *(const f32x4*)(tp + 4);
            union { bf16x8 v; unsigned short u[8]; } H, L;
            #pragma unroll
            for (int i = 0; i < 4; ++i) {
                split_bf16(v0[i], H.u[i], L.u[i]);
                split_bf16(v1[i], H.u[i + 4], L.u[i + 4]);
            }
            ah[rt] = H.v; al[rt] = L.v;
        }
        #pragma unroll
        for (int nt = 0; nt < NT2; ++nt) {
            const unsigned short* pb = PW2 + (((size_t)kc * NT2 + nt) * 64 + l) * 8;
            bf16x8 bh = *(const bf16x8*)pb;
            bf16x8 bl = *(const bf16x8*)(pb + (size_t)KC2 * NT2 * 512);
            #pragma unroll
            for (int rt = 0; rt < 2; ++rt) {
                acc2[rt][nt] = __builtin_amdgcn_mfma_f32_16x16x32_bf16(ah[rt], bh, acc2[rt][nt], 0, 0, 0);
                acc2[rt][nt] = __builtin_amdgcn_mfma_f32_16x16x32_bf16(ah[rt], bl, acc2[rt][nt], 0, 0, 0);
                acc2[rt][nt] = __builtin_amdgcn_mfma_f32_16x16x32_bf16(al[rt], bh, acc2[rt][nt], 0, 0, 0);
            }
        }
    }

    // epilogue 2: bias + leaky -> global
    #pragma unroll
    for (int nt = 0; nt < NT2; ++nt) {
        float bb = B2[nt * 16 + lr];
        #pragma unroll
        for (int rt = 0; rt < 2; ++rt) {
            #pragma unroll
            for (int r = 0; r < 4; ++r) {
                int row = m0 + rt * 16 + lg * 4 + r;
                if (row < nrows) {
                    float v = acc2[rt][nt][r] + bb;
                    v = v > 0.f ? v : 0.01f * v;
                    Out[(size_t)row * N2 + nt * 16 + lr] = (OutT)v;
                }
            }
        }
    }
}

// ---------------- launch ----------------

extern "C" void kernel_launch(void* const* d_in, const int* in_sizes, int n_in,
                              void* d_out, int out_size, void* d_ws, size_t ws_size,
                              hipStream_t stream) {
    const float* x   = (const float*)d_in[0];
    const int*   src = (const int*)d_in[1];
    const int*   dst = (const int*)d_in[2];
    const float* eps = (const float*)d_in[3];
    const float* w1s = (const float*)d_in[4];
    const float* b1s = (const float*)d_in[5];
    const float* w2s = (const float*)d_in[6];
    const float* b2s = (const float*)d_in[7];
    const float* wf1 = (const float*)d_in[8];
    const float* bf1 = (const float*)d_in[9];
    const float* wf2 = (const float*)d_in[10];
    const float* bf2 = (const float*)d_in[11];

    const int N = in_sizes[0] / NCH;   // 100000
    const int E = in_sizes[1];         // 600000

    auto align256 = [](size_t v) { return (v + 255) & ~(size_t)255; };
    char* p = (char*)d_ws;
    int* off = (int*)p;              p += align256((size_t)(N + 1) * 4);
    int* part = (int*)p;             p += align256(1024 * 4);
    int* csr = (int*)p;              p += align256((size_t)E * 4);
    __half* xh = (__half*)p;         p += align256((size_t)N * NCH * 2);
    __half* hh = (__half*)p;         p += align256((size_t)N * NCH * 2);
    unsigned short* zh = (unsigned short*)p; p += (size_t)N * NCH * 2;
    unsigned short* zl = (unsigned short*)p; p += (size_t)N * NCH * 2;
    unsigned short* pw1 = (unsigned short*)p; p += 3 * 65536;
    unsigned short* pw2 = (unsigned short*)p; p += 3 * 65536;
    unsigned short* pwf1 = (unsigned short*)p; p += 32768;
    unsigned short* pwf2 = (unsigned short*)p;

    // CSR build
    const int nScan = N + 1;
    const int nTiles = (nScan + 2047) / 2048;
    hipMemsetAsync(off, 0, (size_t)nScan * 4, stream);
    gin_deg_kernel<<<(E + 255) / 256, 256, 0, stream>>>(dst, off, E);
    gin_scan1<<<nTiles, 256, 0, stream>>>(off, part, nScan);
    gin_scan2<<<1, 256, 0, stream>>>(part, nTiles);
    gin_scan3<<<nTiles, 256, 0, stream>>>(off, part, nScan);
    gin_fill_kernel<<<(E + 255) / 256, 256, 0, stream>>>(src, dst, off, csr, E);

    // x -> fp16 copy for gathering
    const int n4 = N * NCH / 4;
    gin_f2h_kernel<<<(n4 + 255) / 256, 256, 0, stream>>>(x, xh, n4);

    // pack weights
    for (int layer = 0; layer < 3; ++layer) {
        gin_pack_kernel<<<128, 256, 0, stream>>>(w1s + (size_t)layer * 128 * 128, 128, 128,
                                                 (unsigned short*)((char*)pw1 + (size_t)layer * 65536));
        gin_pack_kernel<<<128, 256, 0, stream>>>(w2s + (size_t)layer * 128 * 128, 128, 128,
                                                 (unsigned short*)((char*)pw2 + (size_t)layer * 65536));
    }
    gin_pack_kernel<<<64, 256, 0, stream>>>(wf1, 128, 64, pwf1);
    gin_pack_kernel<<<32, 256, 0, stream>>>(wf2, 64, 64, pwf2);

    const int aggGrid = (N + 7) / 8;
    const int mlpGrid = (N + 127) / 128;

    gin_agg_kernel<<<aggGrid, 256, 0, stream>>>(xh, off, csr, eps, 0, zh, zl, N);
    gin_mlp_mfma<128, 128, __half><<<mlpGrid, 256, 0, stream>>>(
        zh, zl, pw1, b1s, pw2, b2s, hh, N);
    for (int layer = 1; layer < 3; ++layer) {
        gin_agg_kernel<<<aggGrid, 256, 0, stream>>>(hh, off, csr, eps, layer, zh, zl, N);
        gin_mlp_mfma<128, 128, __half><<<mlpGrid, 256, 0, stream>>>(
            zh, zl,
            (unsigned short*)((char*)pw1 + (size_t)layer * 65536), b1s + (size_t)layer * 128,
            (unsigned short*)((char*)pw2 + (size_t)layer * 65536), b2s + (size_t)layer * 128,
            hh, N);
    }
    gin_agg_kernel<<<aggGrid, 256, 0, stream>>>(hh, off, csr, eps, 3, zh, zl, N);
    gin_mlp_mfma<64, 64, float><<<mlpGrid, 256, 0, stream>>>(
        zh, zl, pwf1, bf1, pwf2, bf2, (float*)d_out, N);
}

// Round 7
// 472.461 us; speedup vs baseline: 1.0431x; 1.0431x over previous
//
#include <hip/hip_runtime.h>
#include <hip/hip_fp16.h>

#define NCH 128

typedef short bf16x8 __attribute__((ext_vector_type(8)));
typedef float f32x4 __attribute__((ext_vector_type(4)));

__device__ __forceinline__ unsigned short f32_to_bf16_rne(float f) {
    unsigned u = __float_as_uint(f);
    unsigned r = u + 0x7FFFu + ((u >> 16) & 1u);
    return (unsigned short)(r >> 16);
}
// trunc-split: hi = trunc16(f), lo = rne(f - hi). |lo| <= 2^-8|f|.
__device__ __forceinline__ void split_bf16(float f, unsigned short& hi, unsigned short& lo) {
    unsigned u = __float_as_uint(f);
    hi = (unsigned short)(u >> 16);
    float l = f - __uint_as_float(u & 0xFFFF0000u);
    lo = f32_to_bf16_rne(l);
}

// ---------------- CSR build ----------------
// After deg+scan: off[d] = start of node d. fill bumps off[d]; after: off[d] = inclusive end.

__global__ void gin_deg_kernel(const int* __restrict__ dst, int* __restrict__ off, int E) {
    int e = blockIdx.x * 256 + threadIdx.x;
    if (e < E) atomicAdd(&off[dst[e] + 1], 1);
}

__global__ void gin_scan1(const int* __restrict__ off, int* __restrict__ part, int n) {
    __shared__ int red[256];
    int t = threadIdx.x;
    int base = blockIdx.x * 2048 + t * 8;
    int s = 0;
    if (base + 8 <= n) {
        #pragma unroll
        for (int i = 0; i < 8; ++i) s += off[base + i];
    } else {
        for (int i = 0; i < 8; ++i) { int idx = base + i; if (idx < n) s += off[idx]; }
    }
    red[t] = s;
    __syncthreads();
    #pragma unroll
    for (int o = 128; o > 0; o >>= 1) {
        if (t < o) red[t] += red[t + o];
        __syncthreads();
    }
    if (t == 0) part[blockIdx.x] = red[0];
}

__global__ void gin_scan2(int* __restrict__ part, int nb) {
    __shared__ int sh[256];
    int t = threadIdx.x;
    int v = (t < nb) ? part[t] : 0;
    sh[t] = v;
    __syncthreads();
    #pragma unroll
    for (int o = 1; o < 256; o <<= 1) {
        int u = (t >= o) ? sh[t - o] : 0;
        __syncthreads();
        sh[t] += u;
        __syncthreads();
    }
    if (t < nb) part[t] = sh[t] - v;
}

__global__ void gin_scan3(int* __restrict__ off, const int* __restrict__ part, int n) {
    __shared__ int red[256];
    int t = threadIdx.x;
    int base = blockIdx.x * 2048 + t * 8;
    int loc[8];
    int s = 0;
    #pragma unroll
    for (int i = 0; i < 8; ++i) {
        int idx = base + i;
        int v = (idx < n) ? off[idx] : 0;
        s += v;
        loc[i] = s;
    }
    red[t] = s;
    __syncthreads();
    #pragma unroll
    for (int o = 1; o < 256; o <<= 1) {
        int u = (t >= o) ? red[t - o] : 0;
        __syncthreads();
        red[t] += u;
        __syncthreads();
    }
    int offset = part[blockIdx.x] + red[t] - s;
    #pragma unroll
    for (int i = 0; i < 8; ++i) {
        int idx = base + i;
        if (idx < n) off[idx] = loc[i] + offset;
    }
}

__global__ void gin_fill_kernel(const int* __restrict__ src, const int* __restrict__ dst,
                                int* __restrict__ off, int* __restrict__ csr, int E) {
    int e = blockIdx.x * 256 + threadIdx.x;
    if (e < E) {
        int d = dst[e];
        int p = atomicAdd(&off[d], 1);
        csr[p] = src[e];
    }
}

// ---------------- x -> fp16 ----------------
__global__ void gin_f2h_kernel(const float* __restrict__ x, __half* __restrict__ xh, int n4) {
    int i = blockIdx.x * 256 + threadIdx.x;
    if (i >= n4) return;
    float4 v = ((const float4*)x)[i];
    union { __half h[4]; uint2 u; } o;
    o.h[0] = __float2half(v.x); o.h[1] = __float2half(v.y);
    o.h[2] = __float2half(v.z); o.h[3] = __float2half(v.w);
    ((uint2*)xh)[i] = o.u;
}

// ---------------- weight pre-pack into MFMA B-fragment order (bf16 hi/lo) ----------------
__global__ void gin_pack_kernel(const float* __restrict__ W, int K, int N,
                                unsigned short* __restrict__ out) {
    int idx = blockIdx.x * 256 + threadIdx.x;
    int KC = K / 32, NT = N / 16;
    int total = 2 * KC * NT * 64 * 8;
    if (idx >= total) return;
    int j = idx & 7;
    int l = (idx >> 3) & 63;
    int v = idx >> 9;
    int nt = v % NT; v /= NT;
    int kc = v % KC;
    int spl = v / KC;
    int k = kc * 32 + (l >> 4) * 8 + j;
    int n = nt * 16 + (l & 15);
    float w = W[(size_t)k * N + n];
    unsigned short hi, lo;
    split_bf16(w, hi, lo);
    out[idx] = (spl == 0) ? hi : lo;
}

// ---------------- fused GINConv layer: gather+mean+MLP in one kernel ----------------
// 256 threads = 4 waves, 64 nodes/block.
// Phase 1: 4 threads/node x 32 ch gather (16B loads, unroll-2 edges);
//          z = (1+eps)h + mean split to bf16 hi/lo -> LDS (64 x 136 shorts x2).
// Phase 2 (after one barrier): round-5 MLP, 16 rows/wave, A-frags from LDS,
//          GEMM1->GEMM2 via wave-private scratch (no more barriers).
// Rows >= nrows: LDS garbage flows only into masked-out C rows (A-row == C-row).
template <int N1, int N2, typename OutT>
__global__ __launch_bounds__(256)
void gin_fused(const __half* __restrict__ Hin, const int* __restrict__ offend,
               const int* __restrict__ csr, const float* __restrict__ eps_p, int layer,
               const unsigned short* __restrict__ PW1, const float* __restrict__ B1,
               const unsigned short* __restrict__ PW2, const float* __restrict__ B2,
               OutT* __restrict__ Out, int nrows) {
    constexpr int K1 = 128;
    constexpr int KC1 = K1 / 32, NT1 = N1 / 16, KC2 = N1 / 32, NT2 = N2 / 16;
    constexpr int ZS = 136;   // short stride (272B rows, 16B-aligned)
    constexpr int SS = 36;    // scratch f32 row stride
    __shared__ __align__(16) unsigned short ZH[64 * ZS];
    __shared__ __align__(16) unsigned short ZL[64 * ZS];
    __shared__ __align__(16) float Scr[4 * 16 * SS];

    const int tid = threadIdx.x;

    // ---- phase 1: gather ----
    {
        int m = tid >> 2;           // node within block (0..63)
        int q = tid & 3;            // channel quarter: q*32..q*32+31
        int node = blockIdx.x * 64 + m;
        if (node < nrows) {
            int lo = node ? offend[node - 1] : 0;
            int hi = offend[node];
            float s[32];
            #pragma unroll
            for (int i = 0; i < 32; ++i) s[i] = 0.f;
            const size_t qoff = (size_t)q * 32;
            int e = lo;
            for (; e + 1 < hi; e += 2) {
                const uint4* pa = (const uint4*)(Hin + (size_t)csr[e] * NCH + qoff);
                const uint4* pb = (const uint4*)(Hin + (size_t)csr[e + 1] * NCH + qoff);
                uint4 ra[4], rb[4];
                #pragma unroll
                for (int v = 0; v < 4; ++v) { ra[v] = pa[v]; rb[v] = pb[v]; }
                #pragma unroll
                for (int v = 0; v < 4; ++v) {
                    const __half2* ha = (const __half2*)&ra[v];
                    const __half2* hb = (const __half2*)&rb[v];
                    #pragma unroll
                    for (int j = 0; j < 4; ++j) {
                        float2 fa = __half22float2(ha[j]);
                        float2 fb = __half22float2(hb[j]);
                        s[v * 8 + j * 2]     += fa.x + fb.x;
                        s[v * 8 + j * 2 + 1] += fa.y + fb.y;
                    }
                }
            }
            if (e < hi) {
                const uint4* pa = (const uint4*)(Hin + (size_t)csr[e] * NCH + qoff);
                uint4 ra[4];
                #pragma unroll
                for (int v = 0; v < 4; ++v) ra[v] = pa[v];
                #pragma unroll
                for (int v = 0; v < 4; ++v) {
                    const __half2* ha = (const __half2*)&ra[v];
                    #pragma unroll
                    for (int j = 0; j < 4; ++j) {
                        float2 fa = __half22float2(ha[j]);
                        s[v * 8 + j * 2]     += fa.x;
                        s[v * 8 + j * 2 + 1] += fa.y;
                    }
                }
            }
            float invd = 1.0f / fmaxf((float)(hi - lo), 1.0f);
            float e1 = 1.0f + eps_p[layer];
            const uint4* ps = (const uint4*)(Hin + (size_t)node * NCH + qoff);
            union { unsigned short u[32]; uint4 v[4]; } HB, LB;
            #pragma unroll
            for (int v = 0; v < 4; ++v) {
                uint4 rs = ps[v];
                const __half2* hs = (const __half2*)&rs;
                #pragma unroll
                for (int j = 0; j < 4; ++j) {
                    float2 fs = __half22float2(hs[j]);
                    int i0 = v * 8 + j * 2;
                    float z0 = e1 * fs.x + s[i0] * invd;
                    float z1 = e1 * fs.y + s[i0 + 1] * invd;
                    split_bf16(z0, HB.u[i0], LB.u[i0]);
                    split_bf16(z1, HB.u[i0 + 1], LB.u[i0 + 1]);
                }
            }
            uint4* dh = (uint4*)&ZH[m * ZS + q * 32];
            uint4* dl = (uint4*)&ZL[m * ZS + q * 32];
            #pragma unroll
            for (int v = 0; v < 4; ++v) { dh[v] = HB.v[v]; dl[v] = LB.v[v]; }
        }
    }
    __syncthreads();

    // ---- phase 2: fused 2-GEMM MLP (split-bf16, 3 MFMA terms) ----
    const int w = tid >> 6;
    const int l = tid & 63;
    const int lr = l & 15;   // A-row / B-col / C-col within 16x16 tile
    const int lg = l >> 4;   // k-group; C-row = lg*4+r
    const int wrow = w * 16;                 // wave's row band within block
    const int m0 = blockIdx.x * 64 + wrow;
    float* sw = &Scr[w * 16 * SS];

    f32x4 acc[NT1];
    #pragma unroll
    for (int nt = 0; nt < NT1; ++nt) acc[nt] = {0.f, 0.f, 0.f, 0.f};

    #pragma unroll
    for (int kc = 0; kc < KC1; ++kc) {
        bf16x8 ah = *(const bf16x8*)&ZH[(wrow + lr) * ZS + kc * 32 + lg * 8];
        bf16x8 al = *(const bf16x8*)&ZL[(wrow + lr) * ZS + kc * 32 + lg * 8];
        #pragma unroll
        for (int nt = 0; nt < NT1; ++nt) {
            const unsigned short* pb = PW1 + (((size_t)kc * NT1 + nt) * 64 + l) * 8;
            bf16x8 bh = *(const bf16x8*)pb;
            bf16x8 bl = *(const bf16x8*)(pb + (size_t)KC1 * NT1 * 512);
            acc[nt] = __builtin_amdgcn_mfma_f32_16x16x32_bf16(ah, bh, acc[nt], 0, 0, 0);
            acc[nt] = __builtin_amdgcn_mfma_f32_16x16x32_bf16(ah, bl, acc[nt], 0, 0, 0);
            acc[nt] = __builtin_amdgcn_mfma_f32_16x16x32_bf16(al, bh, acc[nt], 0, 0, 0);
        }
    }

    // GEMM2 interleaved with epilogue-1 through wave-private scratch (no barrier)
    f32x4 acc2[NT2];
    #pragma unroll
    for (int nt = 0; nt < NT2; ++nt) acc2[nt] = {0.f, 0.f, 0.f, 0.f};

    #pragma unroll
    for (int kc = 0; kc < KC2; ++kc) {
        #pragma unroll
        for (int t = 0; t < 2; ++t) {
            int nt = kc * 2 + t;
            float bb = B1[nt * 16 + lr];
            #pragma unroll
            for (int r = 0; r < 4; ++r) {
                float v = acc[nt][r] + bb;
                v = v > 0.f ? v : 0.01f * v;
                sw[(lg * 4 + r) * SS + t * 16 + lr] = v;
            }
        }
        const float* tp = &sw[lr * SS + lg * 8];
        f32x4 v0 = *(const f32x4*)tp;
        f32x4 v1 = *(const f32x4*)(tp + 4);
        union { bf16x8 v; unsigned short u[8]; } H, L;
        #pragma unroll
        for (int i = 0; i < 4; ++i) {
            split_bf16(v0[i], H.u[i], L.u[i]);
            split_bf16(v1[i], H.u[i + 4], L.u[i + 4]);
        }
        bf16x8 ah = H.v, al = L.v;
        #pragma unroll
        for (int nt = 0; nt < NT2; ++nt) {
            const unsigned short* pb = PW2 + (((size_t)kc * NT2 + nt) * 64 + l) * 8;
            bf16x8 bh = *(const bf16x8*)pb;
            bf16x8 bl = *(const bf16x8*)(pb + (size_t)KC2 * NT2 * 512);
            acc2[nt] = __builtin_amdgcn_mfma_f32_16x16x32_bf16(ah, bh, acc2[nt], 0, 0, 0);
            acc2[nt] = __builtin_amdgcn_mfma_f32_16x16x32_bf16(ah, bl, acc2[nt], 0, 0, 0);
            acc2[nt] = __builtin_amdgcn_mfma_f32_16x16x32_bf16(al, bh, acc2[nt], 0, 0, 0);
        }
    }

    // epilogue 2: bias + leaky -> global
    #pragma unroll
    for (int nt = 0; nt < NT2; ++nt) {
        float bb = B2[nt * 16 + lr];
        #pragma unroll
        for (int r = 0; r < 4; ++r) {
            int row = m0 + lg * 4 + r;
            if (row < nrows) {
                float v = acc2[nt][r] + bb;
                v = v > 0.f ? v : 0.01f * v;
                Out[(size_t)row * N2 + nt * 16 + lr] = (OutT)v;
            }
        }
    }
}

// ---------------- launch ----------------

extern "C" void kernel_launch(void* const* d_in, const int* in_sizes, int n_in,
                              void* d_out, int out_size, void* d_ws, size_t ws_size,
                              hipStream_t stream) {
    const float* x   = (const float*)d_in[0];
    const int*   src = (const int*)d_in[1];
    const int*   dst = (const int*)d_in[2];
    const float* eps = (const float*)d_in[3];
    const float* w1s = (const float*)d_in[4];
    const float* b1s = (const float*)d_in[5];
    const float* w2s = (const float*)d_in[6];
    const float* b2s = (const float*)d_in[7];
    const float* wf1 = (const float*)d_in[8];
    const float* bf1 = (const float*)d_in[9];
    const float* wf2 = (const float*)d_in[10];
    const float* bf2 = (const float*)d_in[11];

    const int N = in_sizes[0] / NCH;   // 100000
    const int E = in_sizes[1];         // 600000

    auto align256 = [](size_t v) { return (v + 255) & ~(size_t)255; };
    char* p = (char*)d_ws;
    int* off = (int*)p;              p += align256((size_t)(N + 1) * 4);
    int* part = (int*)p;             p += align256(1024 * 4);
    int* csr = (int*)p;              p += align256((size_t)E * 4);
    __half* xh = (__half*)p;         p += align256((size_t)N * NCH * 2);
    __half* h0 = (__half*)p;         p += align256((size_t)N * NCH * 2);
    __half* h1 = (__half*)p;         p += align256((size_t)N * NCH * 2);
    unsigned short* pw1 = (unsigned short*)p; p += 3 * 65536;
    unsigned short* pw2 = (unsigned short*)p; p += 3 * 65536;
    unsigned short* pwf1 = (unsigned short*)p; p += 32768;
    unsigned short* pwf2 = (unsigned short*)p;

    // CSR build
    const int nScan = N + 1;
    const int nTiles = (nScan + 2047) / 2048;
    hipMemsetAsync(off, 0, (size_t)nScan * 4, stream);
    gin_deg_kernel<<<(E + 255) / 256, 256, 0, stream>>>(dst, off, E);
    gin_scan1<<<nTiles, 256, 0, stream>>>(off, part, nScan);
    gin_scan2<<<1, 256, 0, stream>>>(part, nTiles);
    gin_scan3<<<nTiles, 256, 0, stream>>>(off, part, nScan);
    gin_fill_kernel<<<(E + 255) / 256, 256, 0, stream>>>(src, dst, off, csr, E);

    // x -> fp16 copy for gathering
    const int n4 = N * NCH / 4;
    gin_f2h_kernel<<<(n4 + 255) / 256, 256, 0, stream>>>(x, xh, n4);

    // pack weights
    for (int layer = 0; layer < 3; ++layer) {
        gin_pack_kernel<<<128, 256, 0, stream>>>(w1s + (size_t)layer * 128 * 128, 128, 128,
                                                 (unsigned short*)((char*)pw1 + (size_t)layer * 65536));
        gin_pack_kernel<<<128, 256, 0, stream>>>(w2s + (size_t)layer * 128 * 128, 128, 128,
                                                 (unsigned short*)((char*)pw2 + (size_t)layer * 65536));
    }
    gin_pack_kernel<<<64, 256, 0, stream>>>(wf1, 128, 64, pwf1);
    gin_pack_kernel<<<32, 256, 0, stream>>>(wf2, 64, 64, pwf2);

    const int grid = (N + 63) / 64;

    // layer 0: xh -> h0
    gin_fused<128, 128, __half><<<grid, 256, 0, stream>>>(
        xh, off, csr, eps, 0, pw1, b1s, pw2, b2s, h0, N);
    // layer 1: h0 -> h1
    gin_fused<128, 128, __half><<<grid, 256, 0, stream>>>(
        h0, off, csr, eps, 1,
        (unsigned short*)((char*)pw1 + 65536), b1s + 128,
        (unsigned short*)((char*)pw2 + 65536), b2s + 128, h1, N);
    // layer 2: h1 -> h0
    gin_fused<128, 128, __half><<<grid, 256, 0, stream>>>(
        h1, off, csr, eps, 2,
        (unsigned short*)((char*)pw1 + 2 * 65536), b1s + 256,
        (unsigned short*)((char*)pw2 + 2 * 65536), b2s + 256, h0, N);
    // final layer: h0 -> d_out (128 -> 64 -> 64, f32)
    gin_fused<64, 64, float><<<grid, 256, 0, stream>>>(
        h0, off, csr, eps, 3, pwf1, bf1, pwf2, bf2, (float*)d_out, N);
}

// Round 8
// 434.733 us; speedup vs baseline: 1.1337x; 1.0868x over previous
//
#include <hip/hip_runtime.h>
#include <hip/hip_fp16.h>

#define NCH 128

typedef short bf16x8 __attribute__((ext_vector_type(8)));
typedef float f32x4 __attribute__((ext_vector_type(4)));

__device__ __forceinline__ unsigned short f32_to_bf16_rne(float f) {
    unsigned u = __float_as_uint(f);
    unsigned r = u + 0x7FFFu + ((u >> 16) & 1u);
    return (unsigned short)(r >> 16);
}
// trunc-split: hi = trunc16(f), lo = rne(f - hi). |lo| <= 2^-8|f|.
__device__ __forceinline__ void split_bf16(float f, unsigned short& hi, unsigned short& lo) {
    unsigned u = __float_as_uint(f);
    hi = (unsigned short)(u >> 16);
    float l = f - __uint_as_float(u & 0xFFFF0000u);
    lo = f32_to_bf16_rne(l);
}

// ---------------- CSR build ----------------
// After deg+scan: off[d] = start of node d. fill bumps off[d]; after: off[d] = inclusive end.

__global__ void gin_deg_kernel(const int* __restrict__ dst, int* __restrict__ off, int E) {
    int e = blockIdx.x * 256 + threadIdx.x;
    if (e < E) atomicAdd(&off[dst[e] + 1], 1);
}

__global__ void gin_scan1(const int* __restrict__ off, int* __restrict__ part, int n) {
    __shared__ int red[256];
    int t = threadIdx.x;
    int base = blockIdx.x * 2048 + t * 8;
    int s = 0;
    if (base + 8 <= n) {
        #pragma unroll
        for (int i = 0; i < 8; ++i) s += off[base + i];
    } else {
        for (int i = 0; i < 8; ++i) { int idx = base + i; if (idx < n) s += off[idx]; }
    }
    red[t] = s;
    __syncthreads();
    #pragma unroll
    for (int o = 128; o > 0; o >>= 1) {
        if (t < o) red[t] += red[t + o];
        __syncthreads();
    }
    if (t == 0) part[blockIdx.x] = red[0];
}

__global__ void gin_scan2(int* __restrict__ part, int nb) {
    __shared__ int sh[256];
    int t = threadIdx.x;
    int v = (t < nb) ? part[t] : 0;
    sh[t] = v;
    __syncthreads();
    #pragma unroll
    for (int o = 1; o < 256; o <<= 1) {
        int u = (t >= o) ? sh[t - o] : 0;
        __syncthreads();
        sh[t] += u;
        __syncthreads();
    }
    if (t < nb) part[t] = sh[t] - v;
}

__global__ void gin_scan3(int* __restrict__ off, const int* __restrict__ part, int n) {
    __shared__ int red[256];
    int t = threadIdx.x;
    int base = blockIdx.x * 2048 + t * 8;
    int loc[8];
    int s = 0;
    #pragma unroll
    for (int i = 0; i < 8; ++i) {
        int idx = base + i;
        int v = (idx < n) ? off[idx] : 0;
        s += v;
        loc[i] = s;
    }
    red[t] = s;
    __syncthreads();
    #pragma unroll
    for (int o = 1; o < 256; o <<= 1) {
        int u = (t >= o) ? red[t - o] : 0;
        __syncthreads();
        red[t] += u;
        __syncthreads();
    }
    int offset = part[blockIdx.x] + red[t] - s;
    #pragma unroll
    for (int i = 0; i < 8; ++i) {
        int idx = base + i;
        if (idx < n) off[idx] = loc[i] + offset;
    }
}

__global__ void gin_fill_kernel(const int* __restrict__ src, const int* __restrict__ dst,
                                int* __restrict__ off, int* __restrict__ csr, int E) {
    int e = blockIdx.x * 256 + threadIdx.x;
    if (e < E) {
        int d = dst[e];
        int p = atomicAdd(&off[d], 1);
        csr[p] = src[e];
    }
}

// ---------------- x -> fp16 ----------------
__global__ void gin_f2h_kernel(const float* __restrict__ x, __half* __restrict__ xh, int n4) {
    int i = blockIdx.x * 256 + threadIdx.x;
    if (i >= n4) return;
    float4 v = ((const float4*)x)[i];
    union { __half h[4]; uint2 u; } o;
    o.h[0] = __float2half(v.x); o.h[1] = __float2half(v.y);
    o.h[2] = __float2half(v.z); o.h[3] = __float2half(v.w);
    ((uint2*)xh)[i] = o.u;
}

// ---------------- weight pre-pack into MFMA B-fragment order (bf16 hi/lo) ----------------
__global__ void gin_pack_kernel(const float* __restrict__ W, int K, int N,
                                unsigned short* __restrict__ out) {
    int idx = blockIdx.x * 256 + threadIdx.x;
    int KC = K / 32, NT = N / 16;
    int total = 2 * KC * NT * 64 * 8;
    if (idx >= total) return;
    int j = idx & 7;
    int l = (idx >> 3) & 63;
    int v = idx >> 9;
    int nt = v % NT; v /= NT;
    int kc = v % KC;
    int spl = v / KC;
    int k = kc * 32 + (l >> 4) * 8 + j;
    int n = nt * 16 + (l & 15);
    float w = W[(size_t)k * N + n];
    unsigned short hi, lo;
    split_bf16(w, hi, lo);
    out[idx] = (spl == 0) ? hi : lo;
}

// ---------------- fused GINConv layer: register-direct gather + MLP ----------------
// 256 threads = 4 waves, 16 nodes/wave, 64 nodes/block. NO barriers, tiny LDS.
// Thread l=(lg,lr) of wave w gathers node (block*64 + w*16 + lr), channels
// lg*8+{0..7}+32*kc (kc=0..3) -- exactly its MFMA A-fragment slots, so the
// aggregated z goes straight from registers into GEMM1. For fixed kc the 4
// lanes {lr,lr+16,lr+32,lr+48} cover one contiguous 64B segment of a row
// (coalescing groups by address, not lane adjacency). GEMM1->GEMM2 transpose
// via wave-private LDS scratch (DS ops in-order within a wave; round-5-proven).
template <int N1, int N2, typename OutT>
__global__ __launch_bounds__(256)
void gin_fused(const __half* __restrict__ Hin, const int* __restrict__ offend,
               const int* __restrict__ csr, const float* __restrict__ eps_p, int layer,
               const unsigned short* __restrict__ PW1, const float* __restrict__ B1,
               const unsigned short* __restrict__ PW2, const float* __restrict__ B2,
               OutT* __restrict__ Out, int nrows) {
    constexpr int K1 = 128;
    constexpr int KC1 = K1 / 32, NT1 = N1 / 16, KC2 = N1 / 32, NT2 = N2 / 16;
    constexpr int SS = 36;    // scratch f32 row stride
    __shared__ __align__(16) float Scr[4 * 16 * SS];

    const int tid = threadIdx.x;
    const int w = tid >> 6;
    const int l = tid & 63;
    const int lr = l & 15;   // node/row within wave band; A-row / B-col / C-col
    const int lg = l >> 4;   // k-group; A-k = kc*32+lg*8+j; C-row = lg*4+r
    const int m0 = blockIdx.x * 64 + w * 16;
    const int node = m0 + lr;
    float* sw = &Scr[w * 16 * SS];

    // ---- phase 1: gather z-fragment in registers ----
    union { bf16x8 v; unsigned short u[8]; } AH[KC1], AL[KC1];

    if (node < nrows) {
        int lo = node ? offend[node - 1] : 0;
        int hi = offend[node];
        float s[KC1][8];
        #pragma unroll
        for (int kc = 0; kc < KC1; ++kc)
            #pragma unroll
            for (int j = 0; j < 8; ++j) s[kc][j] = 0.f;

        const size_t coff = (size_t)lg * 8;   // channel offset of this thread's slots
        int e = lo;
        for (; e + 1 < hi; e += 2) {
            const uint4* pa = (const uint4*)(Hin + (size_t)csr[e] * NCH + coff);
            const uint4* pb = (const uint4*)(Hin + (size_t)csr[e + 1] * NCH + coff);
            uint4 ra[KC1], rb[KC1];
            #pragma unroll
            for (int kc = 0; kc < KC1; ++kc) { ra[kc] = pa[kc * 4]; rb[kc] = pb[kc * 4]; }
            #pragma unroll
            for (int kc = 0; kc < KC1; ++kc) {
                const __half2* ha = (const __half2*)&ra[kc];
                const __half2* hb = (const __half2*)&rb[kc];
                #pragma unroll
                for (int j = 0; j < 4; ++j) {
                    float2 fa = __half22float2(ha[j]);
                    float2 fb = __half22float2(hb[j]);
                    s[kc][j * 2]     += fa.x + fb.x;
                    s[kc][j * 2 + 1] += fa.y + fb.y;
                }
            }
        }
        if (e < hi) {
            const uint4* pa = (const uint4*)(Hin + (size_t)csr[e] * NCH + coff);
            uint4 ra[KC1];
            #pragma unroll
            for (int kc = 0; kc < KC1; ++kc) ra[kc] = pa[kc * 4];
            #pragma unroll
            for (int kc = 0; kc < KC1; ++kc) {
                const __half2* ha = (const __half2*)&ra[kc];
                #pragma unroll
                for (int j = 0; j < 4; ++j) {
                    float2 fa = __half22float2(ha[j]);
                    s[kc][j * 2]     += fa.x;
                    s[kc][j * 2 + 1] += fa.y;
                }
            }
        }
        float invd = 1.0f / fmaxf((float)(hi - lo), 1.0f);
        float e1 = 1.0f + eps_p[layer];
        const uint4* ps = (const uint4*)(Hin + (size_t)node * NCH + coff);
        #pragma unroll
        for (int kc = 0; kc < KC1; ++kc) {
            uint4 rs = ps[kc * 4];
            const __half2* hs = (const __half2*)&rs;
            #pragma unroll
            for (int j = 0; j < 4; ++j) {
                float2 fs = __half22float2(hs[j]);
                float z0 = e1 * fs.x + s[kc][j * 2] * invd;
                float z1 = e1 * fs.y + s[kc][j * 2 + 1] * invd;
                split_bf16(z0, AH[kc].u[j * 2], AL[kc].u[j * 2]);
                split_bf16(z1, AH[kc].u[j * 2 + 1], AL[kc].u[j * 2 + 1]);
            }
        }
    } else {
        #pragma unroll
        for (int kc = 0; kc < KC1; ++kc) {
            AH[kc].v = (bf16x8){0,0,0,0,0,0,0,0};
            AL[kc].v = (bf16x8){0,0,0,0,0,0,0,0};
        }
    }

    // ---- GEMM1: T = leaky(Z @ W1 + b1) ----
    f32x4 acc[NT1];
    #pragma unroll
    for (int nt = 0; nt < NT1; ++nt) acc[nt] = {0.f, 0.f, 0.f, 0.f};

    #pragma unroll
    for (int kc = 0; kc < KC1; ++kc) {
        #pragma unroll
        for (int nt = 0; nt < NT1; ++nt) {
            const unsigned short* pb = PW1 + (((size_t)kc * NT1 + nt) * 64 + l) * 8;
            bf16x8 bh = *(const bf16x8*)pb;
            bf16x8 bl = *(const bf16x8*)(pb + (size_t)KC1 * NT1 * 512);
            acc[nt] = __builtin_amdgcn_mfma_f32_16x16x32_bf16(AH[kc].v, bh, acc[nt], 0, 0, 0);
            acc[nt] = __builtin_amdgcn_mfma_f32_16x16x32_bf16(AH[kc].v, bl, acc[nt], 0, 0, 0);
            acc[nt] = __builtin_amdgcn_mfma_f32_16x16x32_bf16(AL[kc].v, bh, acc[nt], 0, 0, 0);
        }
    }

    // ---- GEMM2 interleaved with epilogue-1 via wave-private scratch (no barrier) ----
    f32x4 acc2[NT2];
    #pragma unroll
    for (int nt = 0; nt < NT2; ++nt) acc2[nt] = {0.f, 0.f, 0.f, 0.f};

    #pragma unroll
    for (int kc = 0; kc < KC2; ++kc) {
        #pragma unroll
        for (int t = 0; t < 2; ++t) {
            int nt = kc * 2 + t;
            float bb = B1[nt * 16 + lr];
            #pragma unroll
            for (int r = 0; r < 4; ++r) {
                float v = acc[nt][r] + bb;
                v = v > 0.f ? v : 0.01f * v;
                sw[(lg * 4 + r) * SS + t * 16 + lr] = v;
            }
        }
        const float* tp = &sw[lr * SS + lg * 8];
        f32x4 v0 = *(const f32x4*)tp;
        f32x4 v1 = *(const f32x4*)(tp + 4);
        union { bf16x8 v; unsigned short u[8]; } H, L;
        #pragma unroll
        for (int i = 0; i < 4; ++i) {
            split_bf16(v0[i], H.u[i], L.u[i]);
            split_bf16(v1[i], H.u[i + 4], L.u[i + 4]);
        }
        bf16x8 ah = H.v, al = L.v;
        #pragma unroll
        for (int nt = 0; nt < NT2; ++nt) {
            const unsigned short* pb = PW2 + (((size_t)kc * NT2 + nt) * 64 + l) * 8;
            bf16x8 bh = *(const bf16x8*)pb;
            bf16x8 bl = *(const bf16x8*)(pb + (size_t)KC2 * NT2 * 512);
            acc2[nt] = __builtin_amdgcn_mfma_f32_16x16x32_bf16(ah, bh, acc2[nt], 0, 0, 0);
            acc2[nt] = __builtin_amdgcn_mfma_f32_16x16x32_bf16(ah, bl, acc2[nt], 0, 0, 0);
            acc2[nt] = __builtin_amdgcn_mfma_f32_16x16x32_bf16(al, bh, acc2[nt], 0, 0, 0);
        }
    }

    // epilogue 2: bias + leaky -> global
    #pragma unroll
    for (int nt = 0; nt < NT2; ++nt) {
        float bb = B2[nt * 16 + lr];
        #pragma unroll
        for (int r = 0; r < 4; ++r) {
            int row = m0 + lg * 4 + r;
            if (row < nrows) {
                float v = acc2[nt][r] + bb;
                v = v > 0.f ? v : 0.01f * v;
                Out[(size_t)row * N2 + nt * 16 + lr] = (OutT)v;
            }
        }
    }
}

// ---------------- launch ----------------

extern "C" void kernel_launch(void* const* d_in, const int* in_sizes, int n_in,
                              void* d_out, int out_size, void* d_ws, size_t ws_size,
                              hipStream_t stream) {
    const float* x   = (const float*)d_in[0];
    const int*   src = (const int*)d_in[1];
    const int*   dst = (const int*)d_in[2];
    const float* eps = (const float*)d_in[3];
    const float* w1s = (const float*)d_in[4];
    const float* b1s = (const float*)d_in[5];
    const float* w2s = (const float*)d_in[6];
    const float* b2s = (const float*)d_in[7];
    const float* wf1 = (const float*)d_in[8];
    const float* bf1 = (const float*)d_in[9];
    const float* wf2 = (const float*)d_in[10];
    const float* bf2 = (const float*)d_in[11];

    const int N = in_sizes[0] / NCH;   // 100000
    const int E = in_sizes[1];         // 600000

    auto align256 = [](size_t v) { return (v + 255) & ~(size_t)255; };
    char* p = (char*)d_ws;
    int* off = (int*)p;              p += align256((size_t)(N + 1) * 4);
    int* part = (int*)p;             p += align256(1024 * 4);
    int* csr = (int*)p;              p += align256((size_t)E * 4);
    __half* xh = (__half*)p;         p += align256((size_t)N * NCH * 2);
    __half* h0 = (__half*)p;         p += align256((size_t)N * NCH * 2);
    __half* h1 = (__half*)p;         p += align256((size_t)N * NCH * 2);
    unsigned short* pw1 = (unsigned short*)p; p += 3 * 65536;
    unsigned short* pw2 = (unsigned short*)p; p += 3 * 65536;
    unsigned short* pwf1 = (unsigned short*)p; p += 32768;
    unsigned short* pwf2 = (unsigned short*)p;

    // CSR build
    const int nScan = N + 1;
    const int nTiles = (nScan + 2047) / 2048;
    hipMemsetAsync(off, 0, (size_t)nScan * 4, stream);
    gin_deg_kernel<<<(E + 255) / 256, 256, 0, stream>>>(dst, off, E);
    gin_scan1<<<nTiles, 256, 0, stream>>>(off, part, nScan);
    gin_scan2<<<1, 256, 0, stream>>>(part, nTiles);
    gin_scan3<<<nTiles, 256, 0, stream>>>(off, part, nScan);
    gin_fill_kernel<<<(E + 255) / 256, 256, 0, stream>>>(src, dst, off, csr, E);

    // x -> fp16 copy for gathering
    const int n4 = N * NCH / 4;
    gin_f2h_kernel<<<(n4 + 255) / 256, 256, 0, stream>>>(x, xh, n4);

    // pack weights
    for (int layer = 0; layer < 3; ++layer) {
        gin_pack_kernel<<<128, 256, 0, stream>>>(w1s + (size_t)layer * 128 * 128, 128, 128,
                                                 (unsigned short*)((char*)pw1 + (size_t)layer * 65536));
        gin_pack_kernel<<<128, 256, 0, stream>>>(w2s + (size_t)layer * 128 * 128, 128, 128,
                                                 (unsigned short*)((char*)pw2 + (size_t)layer * 65536));
    }
    gin_pack_kernel<<<64, 256, 0, stream>>>(wf1, 128, 64, pwf1);
    gin_pack_kernel<<<32, 256, 0, stream>>>(wf2, 64, 64, pwf2);

    const int grid = (N + 63) / 64;

    // layer 0: xh -> h0
    gin_fused<128, 128, __half><<<grid, 256, 0, stream>>>(
        xh, off, csr, eps, 0, pw1, b1s, pw2, b2s, h0, N);
    // layer 1: h0 -> h1
    gin_fused<128, 128, __half><<<grid, 256, 0, stream>>>(
        h0, off, csr, eps, 1,
        (unsigned short*)((char*)pw1 + 65536), b1s + 128,
        (unsigned short*)((char*)pw2 + 65536), b2s + 128, h1, N);
    // layer 2: h1 -> h0
    gin_fused<128, 128, __half><<<grid, 256, 0, stream>>>(
        h1, off, csr, eps, 2,
        (unsigned short*)((char*)pw1 + 2 * 65536), b1s + 256,
        (unsigned short*)((char*)pw2 + 2 * 65536), b2s + 256, h0, N);
    // final layer: h0 -> d_out (128 -> 64 -> 64, f32)
    gin_fused<64, 64, float><<<grid, 256, 0, stream>>>(
        h0, off, csr, eps, 3, pwf1, bf1, pwf2, bf2, (float*)d_out, N);
}